// Round 11
// baseline (154.816 us; speedup 1.0000x reference)
//
#include <hip/hip_runtime.h>

#define BH_ 16
#define S_ 2048
#define D_ 128
#define KB_ 64
#define QB_ 64

typedef __attribute__((ext_vector_type(4))) float f32x4;
typedef __attribute__((ext_vector_type(8))) short bf16x8;
typedef unsigned short ushort_t;

__device__ __forceinline__ unsigned short f2bf(float x) {
  union { float f; unsigned int u; } v; v.f = x;
  unsigned int r = v.u + 0x7fffu + ((v.u >> 16) & 1u);  // RNE
  return (unsigned short)(r >> 16);
}
__device__ __forceinline__ float bf2f(unsigned short b) {
  union { float f; unsigned int u; } v; v.u = ((unsigned int)b) << 16;
  return v.f;
}

// ---------- k0: K -> fragment-major bf16 hi/lo  AND  V -> PV B-frags ----
// z==0: K chunk (bh,kt,c2,t,lane) at KH + ((bh*32+kt)*16 + c2*4+t)*1024 +
//       lane*16 holds K[kt*64 + t*16 + (lane&15)][c2*32 + (lane>>4)*8 ..+8).
// z==1: V chunk (bh,kt,ks,dt,lane) at VF + ((bh*32+kt)*16 + ks*8+dt)*1024 +
//       lane*16 holds V[kt*64 + ks*32 + (lane>>4)*8 ..+8)[dt*16 + (lane&15)].
__global__ __launch_bounds__(256) void convFrag(const float* __restrict__ K,
                                                const float* __restrict__ V,
                                                ushort_t* __restrict__ KH,
                                                ushort_t* __restrict__ KL,
                                                ushort_t* __restrict__ VF) {
  __shared__ ushort_t tile[64][136];
  const int tid = threadIdx.x;
  const int kt = blockIdx.x, bh = blockIdx.y;
  if (blockIdx.z == 0) {
    const int seg = tid >> 6;      // c2
    const int tl  = tid & 63;      // lane
    const float* src0 = K + ((size_t)bh * S_ + kt * 64 + (tl & 15)) * D_ +
                        seg * 32 + (tl >> 4) * 8;
    char* dh = (char*)KH + ((size_t)(bh * 32 + kt) * 16 + seg * 4) * 1024 + tl * 16;
    char* dl = (char*)KL + ((size_t)(bh * 32 + kt) * 16 + seg * 4) * 1024 + tl * 16;
#pragma unroll
    for (int t = 0; t < 4; ++t) {
      const float* src = src0 + (size_t)t * 16 * D_;
      float4 a = *(const float4*)src;
      float4 b = *(const float4*)(src + 4);
      float xs[8] = {a.x, a.y, a.z, a.w, b.x, b.y, b.z, b.w};
      union { ushort_t u[8]; uint4 v; } H, L;
#pragma unroll
      for (int j = 0; j < 8; ++j) {
        unsigned short h = f2bf(xs[j]);
        H.u[j] = h;
        L.u[j] = f2bf(xs[j] - bf2f(h));
      }
      *(uint4*)(dh + t * 1024) = H.v;
      *(uint4*)(dl + t * 1024) = L.v;
    }
  } else {
    const float* Vb = V + ((size_t)bh * S_ + kt * 64) * D_;
#pragma unroll
    for (int it = 0; it < 8; ++it) {
      int idx = it * 256 + tid;
      int fl = idx * 4;
      int s = fl >> 7, d = fl & 127;
      float4 f = *(const float4*)(Vb + (size_t)s * D_ + d);
      tile[s][d + 0] = f2bf(f.x);
      tile[s][d + 1] = f2bf(f.y);
      tile[s][d + 2] = f2bf(f.z);
      tile[s][d + 3] = f2bf(f.w);
    }
    __syncthreads();
    char* dst0 = (char*)VF + (size_t)(bh * 32 + kt) * 16384;
#pragma unroll
    for (int j = 0; j < 4; ++j) {
      int ci = j * 256 + tid;
      int l = ci & 63, fid = ci >> 6;
      int ks = fid >> 3, dt = fid & 7;
      int s0 = ks * 32 + (l >> 4) * 8;
      int d = dt * 16 + (l & 15);
      union { ushort_t u[8]; uint4 v; } T;
#pragma unroll
      for (int i = 0; i < 8; ++i) T.u[i] = tile[s0 + i][d];
      *(uint4*)(dst0 + (size_t)fid * 1024 + l * 16) = T.v;
    }
  }
}

// ---------- fused kernel: 16 q-rows/block, e lives in LDS only ----------
// 4 waves split k-tiles round-robin; no barriers in k-loop. K/V operand
// fragments are lane-contiguous 1KB bursts from ws (L2-resident).
// Co-resident blocks are phase-ANTI-CORRELATED: consecutive bids alternate
// heavy (long k-loop) / light (long write) row-tiles so one block's
// TCP-read phase overlaps the other's HBM-write phase on the same CU.
__global__ __launch_bounds__(256, 2) void sdpa_fused(
    const float* __restrict__ Q, const ushort_t* __restrict__ KH,
    const ushort_t* __restrict__ KL, const ushort_t* __restrict__ VF,
    float* __restrict__ out, float* __restrict__ attn) {
  __shared__ ushort_t els[32 * 1024];   // 64 KB: [kt][16 rows][64 k] swizzled
  __shared__ float rsLDS[4][16];

  const int tid = threadIdx.x, w = tid >> 6, lane = tid & 63;
  const int g = lane >> 4, c = lane & 15;

  // XCD-aware + phase-alternating mapping.
  const int bid = blockIdx.x;
  const int xcd = bid & 7, slot = bid >> 3;   // slot in [0,256)
  const int bh = xcd + 8 * (slot >> 7);
  const int idx = slot & 127;
  const int rt = (idx & 1) ? (idx >> 1) : (127 - (idx >> 1));
  const int q0 = rt * 16;
  const int nk = (rt >> 2) + 1;               // k-tiles covering k <= q0+15

  const float* Qb = Q + (size_t)bh * S_ * D_;
  const char* KHb = (const char*)KH + (size_t)bh * 32 * 16384;
  const char* KLb = (const char*)KL + (size_t)bh * 32 * 16384;
  const char* VFb = (const char*)VF + (size_t)bh * 32 * 16384;
  float* outb  = out  + (size_t)bh * S_ * D_;
  float* attnb = attn + (size_t)bh * S_ * S_;

  // ---- Q fragments (bf16 hi/lo), row = c ----
  bf16x8 qhi[4], qlo[4];
  {
    const float* qrow = Qb + (size_t)(q0 + c) * D_;
#pragma unroll
    for (int ch = 0; ch < 4; ++ch) {
      const float* src = qrow + ch * 32 + g * 8;
      float4 a = *(const float4*)src;
      float4 b = *(const float4*)(src + 4);
      float xs[8] = {a.x, a.y, a.z, a.w, b.x, b.y, b.z, b.w};
#pragma unroll
      for (int i = 0; i < 8; ++i) {
        unsigned short h = f2bf(xs[i]);
        qhi[ch][i] = (short)h;
        qlo[ch][i] = (short)f2bf(xs[i] - bf2f(h));
      }
    }
  }

  const f32x4 zero4 = {0.f, 0.f, 0.f, 0.f};
  f32x4 oacc[8];
  float rs[4] = {0.f, 0.f, 0.f, 0.f};
#pragma unroll
  for (int dt = 0; dt < 8; ++dt) oacc[dt] = zero4;

  // ---- barrier-free k-loop: wave w owns k-tiles w, w+4, ... ----
  for (int kt = w; kt < nk; kt += 4) {
    const char* kth = KHb + (size_t)kt * 16384 + lane * 16;
    const char* ktl = KLb + (size_t)kt * 16384 + lane * 16;
    const char* ktv = VFb + (size_t)kt * 16384 + lane * 16;

    // V-frag loads hoisted: independent of QK^T, land under the MFMA phase.
    bf16x8 vf0[8], vf1[8];
#pragma unroll
    for (int dt = 0; dt < 8; ++dt) vf0[dt] = *(const bf16x8*)(ktv + dt * 1024);
#pragma unroll
    for (int dt = 0; dt < 8; ++dt) vf1[dt] = *(const bf16x8*)(ktv + (8 + dt) * 1024);

    // QK^T (3-way hi/lo split); frags are 1KB-contiguous bursts
    f32x4 acc[4];
#pragma unroll
    for (int t = 0; t < 4; ++t) acc[t] = zero4;
#pragma unroll
    for (int c2 = 0; c2 < 4; ++c2) {
      bf16x8 kh[4], kl[4];
#pragma unroll
      for (int t = 0; t < 4; ++t) {
        kh[t] = *(const bf16x8*)(kth + (c2 * 4 + t) * 1024);
        kl[t] = *(const bf16x8*)(ktl + (c2 * 4 + t) * 1024);
      }
#pragma unroll
      for (int t = 0; t < 4; ++t)
        acc[t] = __builtin_amdgcn_mfma_f32_16x16x32_bf16(qhi[c2], kh[t], acc[t], 0, 0, 0);
#pragma unroll
      for (int t = 0; t < 4; ++t)
        acc[t] = __builtin_amdgcn_mfma_f32_16x16x32_bf16(qlo[c2], kh[t], acc[t], 0, 0, 0);
#pragma unroll
      for (int t = 0; t < 4; ++t)
        acc[t] = __builtin_amdgcn_mfma_f32_16x16x32_bf16(qhi[c2], kl[t], acc[t], 0, 0, 0);
    }

    // e = exp(s) (0 above diag) -> e-LDS (bf16, per-kt region), rsum accum
#pragma unroll
    for (int r2 = 0; r2 < 4; ++r2) {
      int qrow = g * 4 + r2;
      int qg = q0 + qrow;
#pragma unroll
      for (int t = 0; t < 4; ++t) {
        int kc = t * 16 + c;
        int kg = kt * 64 + kc;
        float e = (kg <= qg) ? __expf(acc[t][r2]) : 0.f;
        rs[r2] += e;
        int off = kt * 2048 + qrow * 128 + ((kc * 2) ^ ((qrow & 7) << 4));
        *(ushort_t*)((char*)els + off) = f2bf(e);
      }
    }

    // PV: A-frag = e from own-wave LDS region (lgkmcnt-ordered); V in regs
    bf16x8 pa[2];
#pragma unroll
    for (int ks = 0; ks < 2; ++ks) {
      int off = kt * 2048 + c * 128 + ((ks * 64 + g * 16) ^ ((c & 7) << 4));
      pa[ks] = *(const bf16x8*)((const char*)els + off);
    }
#pragma unroll
    for (int dt = 0; dt < 8; ++dt)
      oacc[dt] = __builtin_amdgcn_mfma_f32_16x16x32_bf16(pa[0], vf0[dt], oacc[dt], 0, 0, 0);
#pragma unroll
    for (int dt = 0; dt < 8; ++dt)
      oacc[dt] = __builtin_amdgcn_mfma_f32_16x16x32_bf16(pa[1], vf1[dt], oacc[dt], 0, 0, 0);
  }

  // ---- per-wave rsum -> LDS ----
#pragma unroll
  for (int r2 = 0; r2 < 4; ++r2) {
    float s0 = rs[r2];
#pragma unroll
    for (int m = 1; m <= 8; m <<= 1) s0 += __shfl_xor(s0, m, 64);
    if (c == 0) rsLDS[w][g * 4 + r2] = s0;
  }
  __syncthreads();   // all e tiles + rsums visible

  // ---- attn write: full rows (normalized lower-tri, zero upper) ----
  {
    float ivr[4];
#pragma unroll
    for (int rr = 0; rr < 4; ++rr) {
      int r = w * 4 + rr;
      ivr[rr] = 1.0f / (rsLDS[0][r] + rsLDS[1][r] + rsLDS[2][r] + rsLDS[3][r]);
    }
#pragma unroll
    for (int rr = 0; rr < 4; ++rr) {
      const int r = w * 4 + rr;
      const float iv = ivr[rr];
      float* arow = attnb + (size_t)(q0 + r) * S_;
#pragma unroll
      for (int it = 0; it < 4; ++it) {
        int kb8 = it * 512 + lane * 8;
        float4 o0, o1;
        if ((kb8 >> 6) < nk) {
          const char* src = (const char*)els + (kb8 >> 6) * 2048 + r * 128 +
                            (((kb8 & 63) * 2) ^ ((r & 7) << 4));
          bf16x8 ev = *(const bf16x8*)src;
          o0.x = bf2f((ushort_t)ev[0]) * iv; o0.y = bf2f((ushort_t)ev[1]) * iv;
          o0.z = bf2f((ushort_t)ev[2]) * iv; o0.w = bf2f((ushort_t)ev[3]) * iv;
          o1.x = bf2f((ushort_t)ev[4]) * iv; o1.y = bf2f((ushort_t)ev[5]) * iv;
          o1.z = bf2f((ushort_t)ev[6]) * iv; o1.w = bf2f((ushort_t)ev[7]) * iv;
        } else {
          o0 = make_float4(0.f, 0.f, 0.f, 0.f);
          o1 = o0;
        }
        *(float4*)(arow + kb8) = o0;
        *(float4*)(arow + kb8 + 4) = o1;
      }
    }
  }
  __syncthreads();   // attn reads of els done -> reuse els for O reduce

  // ---- O cross-wave reduce (waves 1..3 park partials in els) ----
  if (w > 0) {
    char* base = (char*)els + (size_t)(w - 1) * 8192 + lane * 128;
#pragma unroll
    for (int dt = 0; dt < 8; ++dt)
      *(f32x4*)(base + ((dt * 16) ^ ((lane & 7) << 4))) = oacc[dt];
  }
  __syncthreads();
  if (w == 0) {
    float ivr2[4];
#pragma unroll
    for (int r2 = 0; r2 < 4; ++r2) {
      int r = g * 4 + r2;
      ivr2[r2] = 1.0f / (rsLDS[0][r] + rsLDS[1][r] + rsLDS[2][r] + rsLDS[3][r]);
    }
#pragma unroll
    for (int dt = 0; dt < 8; ++dt) {
      f32x4 o = oacc[dt];
#pragma unroll
      for (int j = 0; j < 3; ++j)
        o += *(const f32x4*)((const char*)els + (size_t)j * 8192 + lane * 128 +
                             ((dt * 16) ^ ((lane & 7) << 4)));
      int d = dt * 16 + c;
#pragma unroll
      for (int r2 = 0; r2 < 4; ++r2) {
        int qg = q0 + g * 4 + r2;
        outb[(size_t)qg * D_ + d] = o[r2] * ivr2[r2] * Qb[(size_t)qg * D_ + d];
      }
    }
  }
}

// ---------- fallback (round-1 kernel, self-contained, known-good) ----------
__global__ __launch_bounds__(256, 2)
void sdpa_fallback(const float* __restrict__ Q, const float* __restrict__ K,
                   const float* __restrict__ V, float* __restrict__ out,
                   float* __restrict__ attn)
{
  __shared__ unsigned short khi[KB_ * D_];
  __shared__ unsigned short klo[KB_ * D_];
  __shared__ unsigned short vts[D_ * KB_];
  __shared__ unsigned short pls[4][16 * KB_];

  const int tid  = threadIdx.x;
  const int w    = tid >> 6;
  const int lane = tid & 63;
  const int g    = lane >> 4;
  const int c    = lane & 15;

  const int bh = blockIdx.y;
  const int qb = (int)gridDim.x - 1 - (int)blockIdx.x;
  const int q0 = qb * QB_;

  const float* Qb = Q + (size_t)bh * S_ * D_;
  const float* Kb = K + (size_t)bh * S_ * D_;
  const float* Vb = V + (size_t)bh * S_ * D_;
  float* outb  = out  + (size_t)bh * S_ * D_;
  float* attnb = attn + (size_t)bh * S_ * S_;

  {
    const int colstart = q0 + QB_;
    for (int r = 0; r < QB_; ++r) {
      float* rowp = attnb + (size_t)(q0 + r) * S_;
      for (int col = colstart + tid * 4; col < S_; col += 1024)
        *(float4*)(rowp + col) = make_float4(0.f, 0.f, 0.f, 0.f);
    }
  }

  bf16x8 qhi[4], qlo[4];
  {
    const float* qrow = Qb + (size_t)(q0 + w * 16 + c) * D_;
#pragma unroll
    for (int ch = 0; ch < 4; ++ch) {
      const float* src = qrow + ch * 32 + g * 8;
      float4 a = *(const float4*)src;
      float4 b = *(const float4*)(src + 4);
      float xs[8] = {a.x, a.y, a.z, a.w, b.x, b.y, b.z, b.w};
#pragma unroll
      for (int i = 0; i < 8; ++i) {
        unsigned short h = f2bf(xs[i]);
        unsigned short l = f2bf(xs[i] - bf2f(h));
        qhi[ch][i] = (short)h;
        qlo[ch][i] = (short)l;
      }
    }
  }

  auto stageK = [&](int kb) {
#pragma unroll
    for (int rr = 0; rr < 8; ++rr) {
      int flat = tid * 4 + rr * 1024;
      int kj = flat >> 7, d0 = flat & 127;
      const float* src = Kb + (size_t)(kb * KB_ + kj) * D_ + d0;
      float4 f = *(const float4*)src;
      unsigned short h0 = f2bf(f.x), h1 = f2bf(f.y), h2 = f2bf(f.z), h3 = f2bf(f.w);
      unsigned short l0 = f2bf(f.x - bf2f(h0)), l1 = f2bf(f.y - bf2f(h1));
      unsigned short l2 = f2bf(f.z - bf2f(h2)), l3 = f2bf(f.w - bf2f(h3));
      int off = kj * 256 + ((d0 * 2) ^ ((kj & 7) << 4));
      *(uint2*)((char*)khi + off) =
          make_uint2((unsigned)h0 | ((unsigned)h1 << 16), (unsigned)h2 | ((unsigned)h3 << 16));
      *(uint2*)((char*)klo + off) =
          make_uint2((unsigned)l0 | ((unsigned)l1 << 16), (unsigned)l2 | ((unsigned)l3 << 16));
    }
  };

  const f32x4 zero4 = {0.f, 0.f, 0.f, 0.f};
  auto computeS = [&](f32x4* acc) {
#pragma unroll
    for (int t = 0; t < 4; ++t) {
      acc[t] = zero4;
      int row = t * 16 + c;
      int rbase = row * 256;
      int sw = (row & 7) << 4;
#pragma unroll
      for (int c2 = 0; c2 < 4; ++c2) {
        int off = rbase + ((c2 * 64 + g * 16) ^ sw);
        bf16x8 kh_ = *(const bf16x8*)((const char*)khi + off);
        bf16x8 kl_ = *(const bf16x8*)((const char*)klo + off);
        acc[t] = __builtin_amdgcn_mfma_f32_16x16x32_bf16(qhi[c2], kh_, acc[t], 0, 0, 0);
        acc[t] = __builtin_amdgcn_mfma_f32_16x16x32_bf16(qhi[c2], kl_, acc[t], 0, 0, 0);
        acc[t] = __builtin_amdgcn_mfma_f32_16x16x32_bf16(qlo[c2], kh_, acc[t], 0, 0, 0);
      }
    }
  };

  float rsum[4] = {0.f, 0.f, 0.f, 0.f};
  for (int kb = 0; kb <= qb; ++kb) {
    __syncthreads();
    stageK(kb);
    __syncthreads();
    f32x4 acc[4];
    computeS(acc);
#pragma unroll
    for (int r2 = 0; r2 < 4; ++r2) {
      int qg = q0 + w * 16 + g * 4 + r2;
      float s0 = 0.f;
#pragma unroll
      for (int t = 0; t < 4; ++t) {
        int kg = kb * KB_ + t * 16 + c;
        float e = (kg <= qg) ? __expf(acc[t][r2]) : 0.f;
        s0 += e;
      }
#pragma unroll
      for (int m = 1; m <= 8; m <<= 1) s0 += __shfl_xor(s0, m, 64);
      rsum[r2] += s0;
    }
  }
  float invl[4];
#pragma unroll
  for (int r2 = 0; r2 < 4; ++r2) invl[r2] = 1.0f / rsum[r2];

  f32x4 oacc[8];
#pragma unroll
  for (int dt = 0; dt < 8; ++dt) oacc[dt] = zero4;

  for (int kb = 0; kb <= qb; ++kb) {
    __syncthreads();
    stageK(kb);
#pragma unroll
    for (int rr = 0; rr < 8; ++rr) {
      int d0 = 4 * (w + 4 * rr);
      const float* src = Vb + (size_t)(kb * KB_ + lane) * D_ + d0;
      float4 f = *(const float4*)src;
      float xs[4] = {f.x, f.y, f.z, f.w};
#pragma unroll
      for (int i = 0; i < 4; ++i) {
        int d = d0 + i;
        int off = d * 128 + ((lane * 2) ^ ((d & 7) << 4));
        *(unsigned short*)((char*)vts + off) = f2bf(xs[i]);
      }
    }
    __syncthreads();

    f32x4 acc[4];
    computeS(acc);

#pragma unroll
    for (int r2 = 0; r2 < 4; ++r2) {
      int qrow = g * 4 + r2;
      int qg = q0 + w * 16 + qrow;
#pragma unroll
      for (int t = 0; t < 4; ++t) {
        int kc = t * 16 + c;
        int kg = kb * KB_ + kc;
        float p = (kg <= qg) ? __expf(acc[t][r2]) * invl[r2] : 0.f;
        attnb[(size_t)qg * S_ + kg] = p;
        int off = qrow * 128 + ((kc * 2) ^ ((qrow & 7) << 4));
        *(unsigned short*)((char*)pls[w] + off) = f2bf(p);
      }
    }
    __syncthreads();

    bf16x8 pa[2];
#pragma unroll
    for (int ks = 0; ks < 2; ++ks) {
      int off = c * 128 + ((ks * 64 + g * 16) ^ ((c & 7) << 4));
      pa[ks] = *(const bf16x8*)((const char*)pls[w] + off);
    }
#pragma unroll
    for (int dt = 0; dt < 8; ++dt) {
      int d = dt * 16 + c;
      int rbase = d * 128;
      int sw = (d & 7) << 4;
#pragma unroll
      for (int ks = 0; ks < 2; ++ks) {
        int off = rbase + ((ks * 64 + g * 16) ^ sw);
        bf16x8 vf = *(const bf16x8*)((const char*)vts + off);
        oacc[dt] = __builtin_amdgcn_mfma_f32_16x16x32_bf16(pa[ks], vf, oacc[dt], 0, 0, 0);
      }
    }
  }

#pragma unroll
  for (int dt = 0; dt < 8; ++dt) {
#pragma unroll
    for (int r2 = 0; r2 < 4; ++r2) {
      int qg = q0 + w * 16 + g * 4 + r2;
      int d = dt * 16 + c;
      float qv = Qb[(size_t)qg * D_ + d];
      outb[(size_t)qg * D_ + d] = oacc[dt][r2] * qv;
    }
  }
}

extern "C" void kernel_launch(void* const* d_in, const int* in_sizes, int n_in,
                              void* d_out, int out_size, void* d_ws, size_t ws_size,
                              hipStream_t stream) {
  const float* q = (const float*)d_in[0];
  const float* k = (const float*)d_in[1];
  const float* v = (const float*)d_in[2];
  float* out  = (float*)d_out;
  float* attn = out + (size_t)BH_ * S_ * D_;

  const size_t nKV = (size_t)BH_ * S_ * D_;   // 4,194,304 elems
  const size_t need = nKV * 2 * 3;            // KH + KL + VF (bf16)

  if (ws_size >= need) {
    ushort_t* KH = (ushort_t*)d_ws;
    ushort_t* KL = KH + nKV;
    ushort_t* VF = KL + nKV;

    convFrag<<<dim3(S_ / 64, BH_, 2), dim3(256), 0, stream>>>(k, v, KH, KL, VF);
    sdpa_fused<<<dim3(BH_ * 128), dim3(256), 0, stream>>>(q, KH, KL, VF, out, attn);
  } else {
    sdpa_fallback<<<dim3(S_ / QB_, BH_), dim3(256), 0, stream>>>(q, k, v, out, attn);
  }
}

// Round 12
// 130.772 us; speedup vs baseline: 1.1839x; 1.1839x over previous
//
#include <hip/hip_runtime.h>

#define BH_ 16
#define S_ 2048
#define D_ 128
#define KB_ 64
#define QB_ 64

typedef __attribute__((ext_vector_type(4))) float f32x4;
typedef __attribute__((ext_vector_type(8))) short bf16x8;
typedef unsigned short ushort_t;

__device__ __forceinline__ unsigned short f2bf(float x) {
  union { float f; unsigned int u; } v; v.f = x;
  unsigned int r = v.u + 0x7fffu + ((v.u >> 16) & 1u);  // RNE
  return (unsigned short)(r >> 16);
}
__device__ __forceinline__ float bf2f(unsigned short b) {
  union { float f; unsigned int u; } v; v.u = ((unsigned int)b) << 16;
  return v.f;
}

// ---------- k0a: K (f32) -> fragment-major bf16 hi/lo ----------
__global__ __launch_bounds__(256) void convKfrag(const float* __restrict__ K,
                                                 ushort_t* __restrict__ KH,
                                                 ushort_t* __restrict__ KL) {
  const int tid = threadIdx.x;
  const int seg = tid >> 6;      // c2
  const int tl  = tid & 63;      // lane
  const int kt = blockIdx.x, bh = blockIdx.y;
  const float* src0 = K + ((size_t)bh * S_ + kt * 64 + (tl & 15)) * D_ +
                      seg * 32 + (tl >> 4) * 8;
  char* dh = (char*)KH + ((size_t)(bh * 32 + kt) * 16 + seg * 4) * 1024 + tl * 16;
  char* dl = (char*)KL + ((size_t)(bh * 32 + kt) * 16 + seg * 4) * 1024 + tl * 16;
#pragma unroll
  for (int t = 0; t < 4; ++t) {
    const float* src = src0 + (size_t)t * 16 * D_;
    float4 a = *(const float4*)src;
    float4 b = *(const float4*)(src + 4);
    float xs[8] = {a.x, a.y, a.z, a.w, b.x, b.y, b.z, b.w};
    union { ushort_t u[8]; uint4 v; } H, L;
#pragma unroll
    for (int j = 0; j < 8; ++j) {
      unsigned short h = f2bf(xs[j]);
      H.u[j] = h;
      L.u[j] = f2bf(xs[j] - bf2f(h));
    }
    *(uint4*)(dh + t * 1024) = H.v;
    *(uint4*)(dl + t * 1024) = L.v;
  }
}

// ---------- k0b: V (f32) -> fragment-major bf16 (PV B-frags) ----------
__global__ __launch_bounds__(256) void convVfrag(const float* __restrict__ V,
                                                 ushort_t* __restrict__ VF) {
  __shared__ ushort_t tile[64][136];
  const int tid = threadIdx.x;
  const int kt = blockIdx.x, bh = blockIdx.y;
  const float* Vb = V + ((size_t)bh * S_ + kt * 64) * D_;
#pragma unroll
  for (int it = 0; it < 8; ++it) {
    int idx = it * 256 + tid;
    int fl = idx * 4;
    int s = fl >> 7, d = fl & 127;
    float4 f = *(const float4*)(Vb + (size_t)s * D_ + d);
    tile[s][d + 0] = f2bf(f.x);
    tile[s][d + 1] = f2bf(f.y);
    tile[s][d + 2] = f2bf(f.z);
    tile[s][d + 3] = f2bf(f.w);
  }
  __syncthreads();
  char* dst0 = (char*)VF + (size_t)(bh * 32 + kt) * 16384;
#pragma unroll
  for (int j = 0; j < 4; ++j) {
    int ci = j * 256 + tid;
    int l = ci & 63, fid = ci >> 6;
    int ks = fid >> 3, dt = fid & 7;
    int s0 = ks * 32 + (l >> 4) * 8;
    int d = dt * 16 + (l & 15);
    union { ushort_t u[8]; uint4 v; } T;
#pragma unroll
    for (int i = 0; i < 8; ++i) T.u[i] = tile[s0 + i][d];
    *(uint4*)(dst0 + (size_t)fid * 1024 + l * 16) = T.v;
  }
}

// ---------- fused kernel: 16 q-rows/block, e lives in LDS only ----------
// Co-resident blocks are (bid, bid+256) = (slot, slot+32). Map idx so every
// such pair is (heavy k-loop, light/write-heavy) with nk-sum ~= 33:
// one block's TCP-read phase overlaps the other's HBM-write phase, and
// per-CU slot-pair work is uniform (no tail).
__global__ __launch_bounds__(256, 2) void sdpa_fused(
    const float* __restrict__ Q, const ushort_t* __restrict__ KH,
    const ushort_t* __restrict__ KL, const ushort_t* __restrict__ VF,
    float* __restrict__ out, float* __restrict__ attn) {
  __shared__ ushort_t els[32 * 1024];   // 64 KB: [kt][16 rows][64 k] swizzled
  __shared__ float rsLDS[4][16];

  const int tid = threadIdx.x, w = tid >> 6, lane = tid & 63;
  const int g = lane >> 4, c = lane & 15;

  const int bid = blockIdx.x;
  const int xcd = bid & 7, slot = bid >> 3;   // slot in [0,256)
  const int bh = xcd + 8 * (slot >> 7);
  const int idx = slot & 127;
  const int half = idx >> 5, j = idx & 31;
  const int rt = (half == 0) ? (127 - j)      // nk 25..32  (launches first)
               : (half == 1) ? j              // nk 1..8    (pairs with half0)
               : (half == 2) ? (95 - j)       // nk 17..24
                             : (32 + j);      // nk 9..16   (pairs with half2)
  const int q0 = rt * 16;
  const int nk = (rt >> 2) + 1;               // k-tiles covering k <= q0+15

  const float* Qb = Q + (size_t)bh * S_ * D_;
  const char* KHb = (const char*)KH + (size_t)bh * 32 * 16384;
  const char* KLb = (const char*)KL + (size_t)bh * 32 * 16384;
  const char* VFb = (const char*)VF + (size_t)bh * 32 * 16384;
  float* outb  = out  + (size_t)bh * S_ * D_;
  float* attnb = attn + (size_t)bh * S_ * S_;

  // ---- Q fragments (bf16 hi/lo), row = c ----
  bf16x8 qhi[4], qlo[4];
  {
    const float* qrow = Qb + (size_t)(q0 + c) * D_;
#pragma unroll
    for (int ch = 0; ch < 4; ++ch) {
      const float* src = qrow + ch * 32 + g * 8;
      float4 a = *(const float4*)src;
      float4 b = *(const float4*)(src + 4);
      float xs[8] = {a.x, a.y, a.z, a.w, b.x, b.y, b.z, b.w};
#pragma unroll
      for (int i = 0; i < 8; ++i) {
        unsigned short h = f2bf(xs[i]);
        qhi[ch][i] = (short)h;
        qlo[ch][i] = (short)f2bf(xs[i] - bf2f(h));
      }
    }
  }

  const f32x4 zero4 = {0.f, 0.f, 0.f, 0.f};
  f32x4 oacc[8];
  float rs[4] = {0.f, 0.f, 0.f, 0.f};
#pragma unroll
  for (int dt = 0; dt < 8; ++dt) oacc[dt] = zero4;

  // ---- barrier-free k-loop: wave w owns k-tiles w, w+4, ... ----
  for (int kt = w; kt < nk; kt += 4) {
    const char* kth = KHb + (size_t)kt * 16384 + lane * 16;
    const char* ktl = KLb + (size_t)kt * 16384 + lane * 16;
    const char* ktv = VFb + (size_t)kt * 16384 + lane * 16;

    // V-frag loads hoisted: independent of QK^T, land under the MFMA phase.
    bf16x8 vf0[8], vf1[8];
#pragma unroll
    for (int dt = 0; dt < 8; ++dt) vf0[dt] = *(const bf16x8*)(ktv + dt * 1024);
#pragma unroll
    for (int dt = 0; dt < 8; ++dt) vf1[dt] = *(const bf16x8*)(ktv + (8 + dt) * 1024);

    // QK^T (3-way hi/lo split); frags are 1KB-contiguous bursts
    f32x4 acc[4];
#pragma unroll
    for (int t = 0; t < 4; ++t) acc[t] = zero4;
#pragma unroll
    for (int c2 = 0; c2 < 4; ++c2) {
      bf16x8 kh[4], kl[4];
#pragma unroll
      for (int t = 0; t < 4; ++t) {
        kh[t] = *(const bf16x8*)(kth + (c2 * 4 + t) * 1024);
        kl[t] = *(const bf16x8*)(ktl + (c2 * 4 + t) * 1024);
      }
#pragma unroll
      for (int t = 0; t < 4; ++t)
        acc[t] = __builtin_amdgcn_mfma_f32_16x16x32_bf16(qhi[c2], kh[t], acc[t], 0, 0, 0);
#pragma unroll
      for (int t = 0; t < 4; ++t)
        acc[t] = __builtin_amdgcn_mfma_f32_16x16x32_bf16(qlo[c2], kh[t], acc[t], 0, 0, 0);
#pragma unroll
      for (int t = 0; t < 4; ++t)
        acc[t] = __builtin_amdgcn_mfma_f32_16x16x32_bf16(qhi[c2], kl[t], acc[t], 0, 0, 0);
    }

    // e = exp(s) (0 above diag) -> e-LDS (bf16, per-kt region), rsum accum
#pragma unroll
    for (int r2 = 0; r2 < 4; ++r2) {
      int qrow = g * 4 + r2;
      int qg = q0 + qrow;
#pragma unroll
      for (int t = 0; t < 4; ++t) {
        int kc = t * 16 + c;
        int kg = kt * 64 + kc;
        float e = (kg <= qg) ? __expf(acc[t][r2]) : 0.f;
        rs[r2] += e;
        int off = kt * 2048 + qrow * 128 + ((kc * 2) ^ ((qrow & 7) << 4));
        *(ushort_t*)((char*)els + off) = f2bf(e);
      }
    }

    // PV: A-frag = e from own-wave LDS region (lgkmcnt-ordered); V in regs
    bf16x8 pa[2];
#pragma unroll
    for (int ks = 0; ks < 2; ++ks) {
      int off = kt * 2048 + c * 128 + ((ks * 64 + g * 16) ^ ((c & 7) << 4));
      pa[ks] = *(const bf16x8*)((const char*)els + off);
    }
#pragma unroll
    for (int dt = 0; dt < 8; ++dt)
      oacc[dt] = __builtin_amdgcn_mfma_f32_16x16x32_bf16(pa[0], vf0[dt], oacc[dt], 0, 0, 0);
#pragma unroll
    for (int dt = 0; dt < 8; ++dt)
      oacc[dt] = __builtin_amdgcn_mfma_f32_16x16x32_bf16(pa[1], vf1[dt], oacc[dt], 0, 0, 0);
  }

  // ---- per-wave rsum -> LDS ----
#pragma unroll
  for (int r2 = 0; r2 < 4; ++r2) {
    float s0 = rs[r2];
#pragma unroll
    for (int m = 1; m <= 8; m <<= 1) s0 += __shfl_xor(s0, m, 64);
    if (c == 0) rsLDS[w][g * 4 + r2] = s0;
  }
  __syncthreads();   // all e tiles + rsums visible

  // ---- attn write: full rows (normalized lower-tri, zero upper) ----
  {
    float ivr[4];
#pragma unroll
    for (int rr = 0; rr < 4; ++rr) {
      int r = w * 4 + rr;
      ivr[rr] = 1.0f / (rsLDS[0][r] + rsLDS[1][r] + rsLDS[2][r] + rsLDS[3][r]);
    }
#pragma unroll
    for (int rr = 0; rr < 4; ++rr) {
      const int r = w * 4 + rr;
      const float iv = ivr[rr];
      float* arow = attnb + (size_t)(q0 + r) * S_;
#pragma unroll
      for (int it = 0; it < 4; ++it) {
        int kb8 = it * 512 + lane * 8;
        float4 o0, o1;
        if ((kb8 >> 6) < nk) {
          const char* src = (const char*)els + (kb8 >> 6) * 2048 + r * 128 +
                            (((kb8 & 63) * 2) ^ ((r & 7) << 4));
          bf16x8 ev = *(const bf16x8*)src;
          o0.x = bf2f((ushort_t)ev[0]) * iv; o0.y = bf2f((ushort_t)ev[1]) * iv;
          o0.z = bf2f((ushort_t)ev[2]) * iv; o0.w = bf2f((ushort_t)ev[3]) * iv;
          o1.x = bf2f((ushort_t)ev[4]) * iv; o1.y = bf2f((ushort_t)ev[5]) * iv;
          o1.z = bf2f((ushort_t)ev[6]) * iv; o1.w = bf2f((ushort_t)ev[7]) * iv;
        } else {
          o0 = make_float4(0.f, 0.f, 0.f, 0.f);
          o1 = o0;
        }
        *(float4*)(arow + kb8) = o0;
        *(float4*)(arow + kb8 + 4) = o1;
      }
    }
  }
  __syncthreads();   // attn reads of els done -> reuse els for O reduce

  // ---- O cross-wave reduce (waves 1..3 park partials in els) ----
  if (w > 0) {
    char* base = (char*)els + (size_t)(w - 1) * 8192 + lane * 128;
#pragma unroll
    for (int dt = 0; dt < 8; ++dt)
      *(f32x4*)(base + ((dt * 16) ^ ((lane & 7) << 4))) = oacc[dt];
  }
  __syncthreads();
  if (w == 0) {
    float ivr2[4];
#pragma unroll
    for (int r2 = 0; r2 < 4; ++r2) {
      int r = g * 4 + r2;
      ivr2[r2] = 1.0f / (rsLDS[0][r] + rsLDS[1][r] + rsLDS[2][r] + rsLDS[3][r]);
    }
#pragma unroll
    for (int dt = 0; dt < 8; ++dt) {
      f32x4 o = oacc[dt];
#pragma unroll
      for (int j2 = 0; j2 < 3; ++j2)
        o += *(const f32x4*)((const char*)els + (size_t)j2 * 8192 + lane * 128 +
                             ((dt * 16) ^ ((lane & 7) << 4)));
      int d = dt * 16 + c;
#pragma unroll
      for (int r2 = 0; r2 < 4; ++r2) {
        int qg = q0 + g * 4 + r2;
        outb[(size_t)qg * D_ + d] = o[r2] * ivr2[r2] * Qb[(size_t)qg * D_ + d];
      }
    }
  }
}

// ---------- fallback (round-1 kernel, self-contained, known-good) ----------
__global__ __launch_bounds__(256, 2)
void sdpa_fallback(const float* __restrict__ Q, const float* __restrict__ K,
                   const float* __restrict__ V, float* __restrict__ out,
                   float* __restrict__ attn)
{
  __shared__ unsigned short khi[KB_ * D_];
  __shared__ unsigned short klo[KB_ * D_];
  __shared__ unsigned short vts[D_ * KB_];
  __shared__ unsigned short pls[4][16 * KB_];

  const int tid  = threadIdx.x;
  const int w    = tid >> 6;
  const int lane = tid & 63;
  const int g    = lane >> 4;
  const int c    = lane & 15;

  const int bh = blockIdx.y;
  const int qb = (int)gridDim.x - 1 - (int)blockIdx.x;
  const int q0 = qb * QB_;

  const float* Qb = Q + (size_t)bh * S_ * D_;
  const float* Kb = K + (size_t)bh * S_ * D_;
  const float* Vb = V + (size_t)bh * S_ * D_;
  float* outb  = out  + (size_t)bh * S_ * D_;
  float* attnb = attn + (size_t)bh * S_ * S_;

  {
    const int colstart = q0 + QB_;
    for (int r = 0; r < QB_; ++r) {
      float* rowp = attnb + (size_t)(q0 + r) * S_;
      for (int col = colstart + tid * 4; col < S_; col += 1024)
        *(float4*)(rowp + col) = make_float4(0.f, 0.f, 0.f, 0.f);
    }
  }

  bf16x8 qhi[4], qlo[4];
  {
    const float* qrow = Qb + (size_t)(q0 + w * 16 + c) * D_;
#pragma unroll
    for (int ch = 0; ch < 4; ++ch) {
      const float* src = qrow + ch * 32 + g * 8;
      float4 a = *(const float4*)src;
      float4 b = *(const float4*)(src + 4);
      float xs[8] = {a.x, a.y, a.z, a.w, b.x, b.y, b.z, b.w};
#pragma unroll
      for (int i = 0; i < 8; ++i) {
        unsigned short h = f2bf(xs[i]);
        unsigned short l = f2bf(xs[i] - bf2f(h));
        qhi[ch][i] = (short)h;
        qlo[ch][i] = (short)l;
      }
    }
  }

  auto stageK = [&](int kb) {
#pragma unroll
    for (int rr = 0; rr < 8; ++rr) {
      int flat = tid * 4 + rr * 1024;
      int kj = flat >> 7, d0 = flat & 127;
      const float* src = Kb + (size_t)(kb * KB_ + kj) * D_ + d0;
      float4 f = *(const float4*)src;
      unsigned short h0 = f2bf(f.x), h1 = f2bf(f.y), h2 = f2bf(f.z), h3 = f2bf(f.w);
      unsigned short l0 = f2bf(f.x - bf2f(h0)), l1 = f2bf(f.y - bf2f(h1));
      unsigned short l2 = f2bf(f.z - bf2f(h2)), l3 = f2bf(f.w - bf2f(h3));
      int off = kj * 256 + ((d0 * 2) ^ ((kj & 7) << 4));
      *(uint2*)((char*)khi + off) =
          make_uint2((unsigned)h0 | ((unsigned)h1 << 16), (unsigned)h2 | ((unsigned)h3 << 16));
      *(uint2*)((char*)klo + off) =
          make_uint2((unsigned)l0 | ((unsigned)l1 << 16), (unsigned)l2 | ((unsigned)l3 << 16));
    }
  };

  const f32x4 zero4 = {0.f, 0.f, 0.f, 0.f};
  auto computeS = [&](f32x4* acc) {
#pragma unroll
    for (int t = 0; t < 4; ++t) {
      acc[t] = zero4;
      int row = t * 16 + c;
      int rbase = row * 256;
      int sw = (row & 7) << 4;
#pragma unroll
      for (int c2 = 0; c2 < 4; ++c2) {
        int off = rbase + ((c2 * 64 + g * 16) ^ sw);
        bf16x8 kh_ = *(const bf16x8*)((const char*)khi + off);
        bf16x8 kl_ = *(const bf16x8*)((const char*)klo + off);
        acc[t] = __builtin_amdgcn_mfma_f32_16x16x32_bf16(qhi[c2], kh_, acc[t], 0, 0, 0);
        acc[t] = __builtin_amdgcn_mfma_f32_16x16x32_bf16(qhi[c2], kl_, acc[t], 0, 0, 0);
        acc[t] = __builtin_amdgcn_mfma_f32_16x16x32_bf16(qlo[c2], kh_, acc[t], 0, 0, 0);
      }
    }
  };

  float rsum[4] = {0.f, 0.f, 0.f, 0.f};
  for (int kb = 0; kb <= qb; ++kb) {
    __syncthreads();
    stageK(kb);
    __syncthreads();
    f32x4 acc[4];
    computeS(acc);
#pragma unroll
    for (int r2 = 0; r2 < 4; ++r2) {
      int qg = q0 + w * 16 + g * 4 + r2;
      float s0 = 0.f;
#pragma unroll
      for (int t = 0; t < 4; ++t) {
        int kg = kb * KB_ + t * 16 + c;
        float e = (kg <= qg) ? __expf(acc[t][r2]) : 0.f;
        s0 += e;
      }
#pragma unroll
      for (int m = 1; m <= 8; m <<= 1) s0 += __shfl_xor(s0, m, 64);
      rsum[r2] += s0;
    }
  }
  float invl[4];
#pragma unroll
  for (int r2 = 0; r2 < 4; ++r2) invl[r2] = 1.0f / rsum[r2];

  f32x4 oacc[8];
#pragma unroll
  for (int dt = 0; dt < 8; ++dt) oacc[dt] = zero4;

  for (int kb = 0; kb <= qb; ++kb) {
    __syncthreads();
    stageK(kb);
#pragma unroll
    for (int rr = 0; rr < 8; ++rr) {
      int d0 = 4 * (w + 4 * rr);
      const float* src = Vb + (size_t)(kb * KB_ + lane) * D_ + d0;
      float4 f = *(const float4*)src;
      float xs[4] = {f.x, f.y, f.z, f.w};
#pragma unroll
      for (int i = 0; i < 4; ++i) {
        int d = d0 + i;
        int off = d * 128 + ((lane * 2) ^ ((d & 7) << 4));
        *(unsigned short*)((char*)vts + off) = f2bf(xs[i]);
      }
    }
    __syncthreads();

    f32x4 acc[4];
    computeS(acc);

#pragma unroll
    for (int r2 = 0; r2 < 4; ++r2) {
      int qrow = g * 4 + r2;
      int qg = q0 + w * 16 + qrow;
#pragma unroll
      for (int t = 0; t < 4; ++t) {
        int kc = t * 16 + c;
        int kg = kb * KB_ + kc;
        float p = (kg <= qg) ? __expf(acc[t][r2]) * invl[r2] : 0.f;
        attnb[(size_t)qg * S_ + kg] = p;
        int off = qrow * 128 + ((kc * 2) ^ ((qrow & 7) << 4));
        *(unsigned short*)((char*)pls[w] + off) = f2bf(p);
      }
    }
    __syncthreads();

    bf16x8 pa[2];
#pragma unroll
    for (int ks = 0; ks < 2; ++ks) {
      int off = c * 128 + ((ks * 64 + g * 16) ^ ((c & 7) << 4));
      pa[ks] = *(const bf16x8*)((const char*)pls[w] + off);
    }
#pragma unroll
    for (int dt = 0; dt < 8; ++dt) {
      int d = dt * 16 + c;
      int rbase = d * 128;
      int sw = (d & 7) << 4;
#pragma unroll
      for (int ks = 0; ks < 2; ++ks) {
        int off = rbase + ((ks * 64 + g * 16) ^ sw);
        bf16x8 vf = *(const bf16x8*)((const char*)vts + off);
        oacc[dt] = __builtin_amdgcn_mfma_f32_16x16x32_bf16(pa[ks], vf, oacc[dt], 0, 0, 0);
      }
    }
  }

#pragma unroll
  for (int dt = 0; dt < 8; ++dt) {
#pragma unroll
    for (int r2 = 0; r2 < 4; ++r2) {
      int qg = q0 + w * 16 + g * 4 + r2;
      int d = dt * 16 + c;
      float qv = Qb[(size_t)qg * D_ + d];
      outb[(size_t)qg * D_ + d] = oacc[dt][r2] * qv;
    }
  }
}

extern "C" void kernel_launch(void* const* d_in, const int* in_sizes, int n_in,
                              void* d_out, int out_size, void* d_ws, size_t ws_size,
                              hipStream_t stream) {
  const float* q = (const float*)d_in[0];
  const float* k = (const float*)d_in[1];
  const float* v = (const float*)d_in[2];
  float* out  = (float*)d_out;
  float* attn = out + (size_t)BH_ * S_ * D_;

  const size_t nKV = (size_t)BH_ * S_ * D_;   // 4,194,304 elems
  const size_t need = nKV * 2 * 3;            // KH + KL + VF (bf16)

  if (ws_size >= need) {
    ushort_t* KH = (ushort_t*)d_ws;
    ushort_t* KL = KH + nKV;
    ushort_t* VF = KL + nKV;

    convKfrag<<<dim3(S_ / 64, BH_), dim3(256), 0, stream>>>(k, KH, KL);
    convVfrag<<<dim3(S_ / 64, BH_), dim3(256), 0, stream>>>(v, VF);
    sdpa_fused<<<dim3(BH_ * 128), dim3(256), 0, stream>>>(q, KH, KL, VF, out, attn);
  } else {
    sdpa_fallback<<<dim3(S_ / QB_, BH_), dim3(256), 0, stream>>>(q, k, v, out, attn);
  }
}